// Round 10
// baseline (175.918 us; speedup 1.0000x reference)
//
#include <hip/hip_runtime.h>

// STKBranch double-softmax attention, f16-MFMA 2-pass, R10:
//   - pass 2: ONE barrier/tile (Ps is wave-private -> lgkmcnt only; Vt double-buffered)
//   - Ps-write swizzle S(lrow)=16*(lrow>>2)+8*(lrow&1): 4-way -> conflict-free b16 writes
//   - carries R9: 512 thr, ROWS=128, XCD swizzle, exp2 folding, pipelined Ks staging
// Math: L = scale*q@k^T ; w = softmax(2L) ; attn = softmax(L*w) ; out = attn@v
// |L| <= ~7 -> no max-subtraction. B=4 H=8 N=2048 D=64 fp32 io.

typedef _Float16 f16;
typedef f16 f16x8 __attribute__((ext_vector_type(8)));
typedef float f32x4 __attribute__((ext_vector_type(4)));

#define MFMA(a, b, c) __builtin_amdgcn_mfma_f32_16x16x32_f16((a), (b), (c), 0, 0, 0)
#define EXP2(x) __builtin_amdgcn_exp2f(x)   // v_exp_f32: D = 2^S0

#define N_CTX 2048
#define DH 64
#define KT 64
#define NKT (N_CTX / KT)
#define ROWS 128          // 8 waves x 16 q-rows
#define QS 72             // Qs/Ks row stride (f16): conflict-free b128 reads

#define C2  2.885390081777927f   // 2*log2(e)
#define L2E 1.442695040888963f   // log2(e)

// Ps swizzle: multiple of 8 (keeps b128 reads contiguous); distinct bits4-5 per q4
#define PS_S(lrow) (16 * ((lrow) >> 2) + 8 * ((lrow) & 1))

__device__ inline unsigned pk(float a, float b) {
    typedef __fp16 fp16x2_t __attribute__((ext_vector_type(2)));
    union { fp16x2_t v; unsigned u; } x;
    x.v = __builtin_amdgcn_cvt_pkrtz(a, b);
    return x.u;
}

__global__ __launch_bounds__(512, 4)
void stk_attn_mfma(const float* __restrict__ qg, const float* __restrict__ kg,
                   const float* __restrict__ vglob, const float* __restrict__ sg,
                   float* __restrict__ og) {
    __shared__ f16 Qs[ROWS * QS];      // 18432 B
    __shared__ f16 Ks[2][KT * QS];     // 18432 B (double-buffered)
    __shared__ f16 Vt[2][DH * KT];     // 16384 B (double-buffered) [d][key ^ 8*(d&7)]
    __shared__ f16 Ps[8][16 * KT];     // 16384 B wave-private [lrow][key ^ PS_S(lrow)]
                                       // total 69632 B -> 2 blocks/CU (160 KB)

    const int tid  = threadIdx.x;
    const int wv   = tid >> 6;        // 0..7
    const int lane = tid & 63;
    const int l15  = lane & 15;
    const int q4   = lane >> 4;
    const int vp   = tid & 31;        // V staging: key pair (2vp, 2vp+1)
    const int vgr  = tid >> 5;        // V staging: d-quad (0..15 -> d = vgr*4..+3)
    const int bh   = blockIdx.x & 31; // XCD swizzle: head h -> blocks h+32j -> XCD h%8
    const int q0   = (blockIdx.x >> 5) * ROWS;
    const float scale = sg[0];

    const float* qb = qg + (size_t)bh * N_CTX * DH;
    const float* kb = kg + (size_t)bh * N_CTX * DH;
    const float* vb = vglob + (size_t)bh * N_CTX * DH;
    float*       ob = og + (size_t)bh * N_CTX * DH;

    // ---- stage Q (scale folded) ----
    #pragma unroll
    for (int it = 0; it < 4; ++it) {
        int idx = it * 512 + tid;
        int row = idx >> 4, c4 = idx & 15;
        float4 v = *(const float4*)&qb[((size_t)(q0 + row)) * DH + c4 * 4];
        *(uint2*)&Qs[row * QS + c4 * 4] =
            make_uint2(pk(v.x * scale, v.y * scale), pk(v.z * scale, v.w * scale));
    }
    __syncthreads();

    // ---- Q A-fragments (loop-invariant): rows wv*16+l15 ----
    f16x8 aq[2];
    #pragma unroll
    for (int kc = 0; kc < 2; ++kc)
        aq[kc] = *(const f16x8*)&Qs[(wv * 16 + l15) * QS + kc * 32 + q4 * 8];

    // =============== PASS 1: s1 = sum exp(2L) ===============
    float s1[4] = {0, 0, 0, 0};
    float4 kr[2];
    #pragma unroll
    for (int it = 0; it < 2; ++it) {
        int idx = it * 512 + tid;
        kr[it] = *(const float4*)&kb[((size_t)(idx >> 4)) * DH + (idx & 15) * 4];
    }
    #pragma unroll
    for (int it = 0; it < 2; ++it) {
        int idx = it * 512 + tid;
        *(uint2*)&Ks[0][(idx >> 4) * QS + (idx & 15) * 4] =
            make_uint2(pk(kr[it].x, kr[it].y), pk(kr[it].z, kr[it].w));
    }
    #pragma unroll
    for (int it = 0; it < 2; ++it) {
        int idx = it * 512 + tid;
        kr[it] = *(const float4*)&kb[((size_t)KT + (idx >> 4)) * DH + (idx & 15) * 4];
    }
    __syncthreads();

    for (int kt = 0; kt < NKT; ++kt) {
        const int cur = kt & 1, nxt = cur ^ 1;
        #pragma unroll
        for (int it = 0; it < 2; ++it) {
            int idx = it * 512 + tid;
            *(uint2*)&Ks[nxt][(idx >> 4) * QS + (idx & 15) * 4] =
                make_uint2(pk(kr[it].x, kr[it].y), pk(kr[it].z, kr[it].w));
        }
        {
            int tn = (kt + 2 < NKT) ? kt + 2 : NKT - 1;
            #pragma unroll
            for (int it = 0; it < 2; ++it) {
                int idx = it * 512 + tid;
                kr[it] = *(const float4*)&kb[((size_t)tn * KT + (idx >> 4)) * DH + (idx & 15) * 4];
            }
        }
        #pragma unroll
        for (int kgi = 0; kgi < 4; ++kgi) {
            f16x8 b0 = *(const f16x8*)&Ks[cur][(kgi * 16 + l15) * QS + 0 * 32 + q4 * 8];
            f16x8 b1 = *(const f16x8*)&Ks[cur][(kgi * 16 + l15) * QS + 1 * 32 + q4 * 8];
            f32x4 acc = {0.f, 0.f, 0.f, 0.f};
            acc = MFMA(aq[0], b0, acc);
            acc = MFMA(aq[1], b1, acc);
            #pragma unroll
            for (int r = 0; r < 4; ++r)
                s1[r] += EXP2(acc[r] * C2);
        }
        __syncthreads();
    }
    float inv1[4];
    #pragma unroll
    for (int s = 0; s < 4; ++s) {
        float v = s1[s];
        v += __shfl_xor(v, 1, 64);
        v += __shfl_xor(v, 2, 64);
        v += __shfl_xor(v, 4, 64);
        v += __shfl_xor(v, 8, 64);
        inv1[s] = L2E / v;      // folds log2e into the e2 argument
    }

    // =============== PASS 2: e2 = exp(L*w), O += e2*V ===============
    float l2[4] = {0, 0, 0, 0};
    f32x4 O[4];
    #pragma unroll
    for (int dt = 0; dt < 4; ++dt) O[dt] = (f32x4){0.f, 0.f, 0.f, 0.f};

    float4 vr[2];
    // prologue: Ks[0]<-K(0), Vt[0]<-V(0); kr<-K(1), vr<-V(1)
    #pragma unroll
    for (int it = 0; it < 2; ++it) {
        int idx = it * 512 + tid;
        kr[it] = *(const float4*)&kb[((size_t)(idx >> 4)) * DH + (idx & 15) * 4];
    }
    #pragma unroll
    for (int it = 0; it < 2; ++it) {
        int idx = it * 512 + tid;
        *(uint2*)&Ks[0][(idx >> 4) * QS + (idx & 15) * 4] =
            make_uint2(pk(kr[it].x, kr[it].y), pk(kr[it].z, kr[it].w));
    }
    {
        const float* vs = vb + ((size_t)2 * vp) * DH + vgr * 4;
        vr[0] = *(const float4*)(vs);
        vr[1] = *(const float4*)(vs + DH);
        #pragma unroll
        for (int j = 0; j < 4; ++j) {
            int d = vgr * 4 + j;
            *(unsigned*)&Vt[0][d * KT + ((2 * vp) ^ (8 * (d & 7)))] =
                pk(((const float*)&vr[0])[j], ((const float*)&vr[1])[j]);
        }
        const float* vs1 = vb + ((size_t)KT + 2 * vp) * DH + vgr * 4;
        vr[0] = *(const float4*)(vs1);
        vr[1] = *(const float4*)(vs1 + DH);
    }
    #pragma unroll
    for (int it = 0; it < 2; ++it) {
        int idx = it * 512 + tid;
        kr[it] = *(const float4*)&kb[((size_t)KT + (idx >> 4)) * DH + (idx & 15) * 4];
    }
    __syncthreads();

    for (int kt = 0; kt < NKT; ++kt) {
        const int cur = kt & 1, nxt = cur ^ 1;
        // stage next tile into the other buffers (overlaps all compute below)
        #pragma unroll
        for (int it = 0; it < 2; ++it) {
            int idx = it * 512 + tid;
            *(uint2*)&Ks[nxt][(idx >> 4) * QS + (idx & 15) * 4] =
                make_uint2(pk(kr[it].x, kr[it].y), pk(kr[it].z, kr[it].w));
        }
        #pragma unroll
        for (int j = 0; j < 4; ++j) {
            int d = vgr * 4 + j;
            *(unsigned*)&Vt[nxt][d * KT + ((2 * vp) ^ (8 * (d & 7)))] =
                pk(((const float*)&vr[0])[j], ((const float*)&vr[1])[j]);
        }
        // QK^T on Ks[cur] + softmax chain + Ps writes (wave-private, lgkmcnt-ordered)
        #pragma unroll
        for (int kgi = 0; kgi < 4; ++kgi) {
            f16x8 b0 = *(const f16x8*)&Ks[cur][(kgi * 16 + l15) * QS + 0 * 32 + q4 * 8];
            f16x8 b1 = *(const f16x8*)&Ks[cur][(kgi * 16 + l15) * QS + 1 * 32 + q4 * 8];
            f32x4 acc = {0.f, 0.f, 0.f, 0.f};
            acc = MFMA(aq[0], b0, acc);
            acc = MFMA(aq[1], b1, acc);
            #pragma unroll
            for (int r = 0; r < 4; ++r) {
                float L  = acc[r];
                float e1 = EXP2(L * C2);
                float e2 = EXP2((L * e1) * inv1[r]);
                l2[r] += e2;
                int lrow = q4 * 4 + r;
                int col  = kgi * 16 + l15;
                Ps[wv][lrow * KT + (col ^ PS_S(lrow))] = (f16)e2;
            }
        }
        // prefetch K(kt+2), V(kt+2) (clamped; loads in flight during PV)
        {
            int tn = (kt + 2 < NKT) ? kt + 2 : NKT - 1;
            #pragma unroll
            for (int it = 0; it < 2; ++it) {
                int idx = it * 512 + tid;
                kr[it] = *(const float4*)&kb[((size_t)tn * KT + (idx >> 4)) * DH + (idx & 15) * 4];
            }
            const float* vs = vb + ((size_t)tn * KT + 2 * vp) * DH + vgr * 4;
            vr[0] = *(const float4*)(vs);
            vr[1] = *(const float4*)(vs + DH);
        }
        // PV from wave-private Ps + Vt[cur] (written last iteration)
        #pragma unroll
        for (int kc = 0; kc < 2; ++kc) {
            int kbase = (kc * 32 + q4 * 8) ^ PS_S(l15);
            f16x8 ap = *(const f16x8*)&Ps[wv][l15 * KT + kbase];
            int kbv = kc * 32 + q4 * 8;
            #pragma unroll
            for (int dt = 0; dt < 4; ++dt) {
                int d = dt * 16 + l15;
                f16x8 bv = *(const f16x8*)&Vt[cur][d * KT + (kbv ^ (8 * (d & 7)))];
                O[dt] = MFMA(ap, bv, O[dt]);
            }
        }
        __syncthreads();   // swap: protects Ks/Vt cur<->nxt for next iteration
    }

    // ---- finalize ----
    float invl2[4];
    #pragma unroll
    for (int s = 0; s < 4; ++s) {
        float v = l2[s];
        v += __shfl_xor(v, 1, 64);
        v += __shfl_xor(v, 2, 64);
        v += __shfl_xor(v, 4, 64);
        v += __shfl_xor(v, 8, 64);
        invl2[s] = 1.0f / v;
    }
    #pragma unroll
    for (int dt = 0; dt < 4; ++dt)
        #pragma unroll
        for (int r = 0; r < 4; ++r) {
            int row = q0 + wv * 16 + q4 * 4 + r;
            ob[(size_t)row * DH + dt * 16 + l15] = O[dt][r] * invl2[r];
        }
}

extern "C" void kernel_launch(void* const* d_in, const int* in_sizes, int n_in,
                              void* d_out, int out_size, void* d_ws, size_t ws_size,
                              hipStream_t stream) {
    const float* q = (const float*)d_in[0];
    const float* k = (const float*)d_in[1];
    const float* v = (const float*)d_in[2];
    const float* s = (const float*)d_in[3];
    float* out = (float*)d_out;
    dim3 grid(32 * 16);   // bh = blockIdx&31 (XCD swizzle), q-tile = blockIdx>>5
    stk_attn_mfma<<<grid, 512, 0, stream>>>(q, k, v, s, out);
}

// Round 11
// 171.107 us; speedup vs baseline: 1.0281x; 1.0281x over previous
//
#include <hip/hip_runtime.h>

// STKBranch double-softmax attention, f16-MFMA 2-pass, R11:
//   - NO XOR swizzles: all LDS tiles row-major with stride 72 f16 (144 B) ->
//     Vt writes bank-bijective, Ps writes 2-way (free), b128 reads at floor,
//     and every ds address = lane base + immediate offset (addr VALU gone)
//   - scale*2*log2e folded into staged Q: acc = 2L*log2e; s1 += exp2(acc);
//     e2 = exp2((acc*e1)*(0.5/s1))  (one mul/logit saved in each pass)
//   - keeps R10 pipeline: Ks/Vt double-buffered, 1 barrier/tile, Ps wave-private
// Math: L = scale*q@k^T ; w = softmax(2L) ; attn = softmax(L*w) ; out = attn@v
// |L| <= ~7 -> no max-subtraction. B=4 H=8 N=2048 D=64 fp32 io.

typedef _Float16 f16;
typedef f16 f16x8 __attribute__((ext_vector_type(8)));
typedef float f32x4 __attribute__((ext_vector_type(4)));

#define MFMA(a, b, c) __builtin_amdgcn_mfma_f32_16x16x32_f16((a), (b), (c), 0, 0, 0)
#define EXP2(x) __builtin_amdgcn_exp2f(x)   // v_exp_f32: D = 2^S0

#define N_CTX 2048
#define DH 64
#define KT 64
#define NKT (N_CTX / KT)
#define ROWS 128          // 8 waves x 16 q-rows
#define QS 72             // universal LDS row stride (f16): 144 B, odd multiple of 16 banks

#define C2 2.885390081777927f    // 2*log2(e), folded into staged Q

__device__ inline unsigned pk(float a, float b) {
    typedef __fp16 fp16x2_t __attribute__((ext_vector_type(2)));
    union { fp16x2_t v; unsigned u; } x;
    x.v = __builtin_amdgcn_cvt_pkrtz(a, b);
    return x.u;
}

__global__ __launch_bounds__(512, 4)
void stk_attn_mfma(const float* __restrict__ qg, const float* __restrict__ kg,
                   const float* __restrict__ vglob, const float* __restrict__ sg,
                   float* __restrict__ og) {
    __shared__ f16 Qs[ROWS * QS];       // 18432 B
    __shared__ f16 Ks[2][KT * QS];      // 18432 B (double-buffered)
    __shared__ f16 Vt[2][DH * QS];      // 18432 B (double-buffered) [d][key], stride 72
    __shared__ f16 Ps[8][16 * QS];      // 18432 B wave-private [lrow][key], stride 72
                                        // total 73728 B -> 2 blocks/CU

    const int tid  = threadIdx.x;
    const int wv   = tid >> 6;        // 0..7
    const int lane = tid & 63;
    const int l15  = lane & 15;
    const int q4   = lane >> 4;
    const int vp   = tid & 31;        // V staging: key pair (2vp, 2vp+1)
    const int vgr  = tid >> 5;        // V staging: d-quad (0..15 -> d = vgr*4..+3)
    const int bh   = blockIdx.x & 31; // XCD swizzle: head h -> blocks h+32j -> XCD h%8
    const int q0   = (blockIdx.x >> 5) * ROWS;
    const float scale2 = sg[0] * C2;  // fold 2*log2e: acc = 2L*log2e

    const float* qb = qg + (size_t)bh * N_CTX * DH;
    const float* kb = kg + (size_t)bh * N_CTX * DH;
    const float* vb = vglob + (size_t)bh * N_CTX * DH;
    float*       ob = og + (size_t)bh * N_CTX * DH;

    // ---- stage Q (scale2 folded) ----
    #pragma unroll
    for (int it = 0; it < 4; ++it) {
        int idx = it * 512 + tid;
        int row = idx >> 4, c4 = idx & 15;
        float4 v = *(const float4*)&qb[((size_t)(q0 + row)) * DH + c4 * 4];
        *(uint2*)&Qs[row * QS + c4 * 4] =
            make_uint2(pk(v.x * scale2, v.y * scale2), pk(v.z * scale2, v.w * scale2));
    }
    __syncthreads();

    // ---- Q A-fragments (loop-invariant): rows wv*16+l15 ----
    f16x8 aq[2];
    #pragma unroll
    for (int kc = 0; kc < 2; ++kc)
        aq[kc] = *(const f16x8*)&Qs[(wv * 16 + l15) * QS + kc * 32 + q4 * 8];

    // loop-invariant LDS lane bases (all ds offsets below are immediates)
    f16* const ks_w  = &Ks[0][0];                    // + staging idx
    const f16* const ks_r = &Ks[0][l15 * QS + q4 * 8];
    f16* const vt_w  = &Vt[0][(vgr * 4) * QS + 2 * vp];
    const f16* const vt_r = &Vt[0][l15 * QS + q4 * 8];
    f16* const ps_w  = &Ps[wv][(q4 * 4) * QS + l15]; // + r*QS + kgi*16
    const f16* const ps_r = &Ps[wv][l15 * QS + q4 * 8];
    const int KSB = KT * QS;                         // Ks/Vt buffer stride (f16)

    // =============== PASS 1: s1 = sum exp(2L) ===============
    float s1[4] = {0, 0, 0, 0};
    float4 kr[2];
    #pragma unroll
    for (int it = 0; it < 2; ++it) {
        int idx = it * 512 + tid;
        kr[it] = *(const float4*)&kb[((size_t)(idx >> 4)) * DH + (idx & 15) * 4];
    }
    #pragma unroll
    for (int it = 0; it < 2; ++it) {
        int idx = it * 512 + tid;
        *(uint2*)&ks_w[(idx >> 4) * QS + (idx & 15) * 4] =
            make_uint2(pk(kr[it].x, kr[it].y), pk(kr[it].z, kr[it].w));
    }
    #pragma unroll
    for (int it = 0; it < 2; ++it) {
        int idx = it * 512 + tid;
        kr[it] = *(const float4*)&kb[((size_t)KT + (idx >> 4)) * DH + (idx & 15) * 4];
    }
    __syncthreads();

    for (int kt = 0; kt < NKT; ++kt) {
        const int cur = (kt & 1) * KSB, nxt = KSB - cur;
        #pragma unroll
        for (int it = 0; it < 2; ++it) {
            int idx = it * 512 + tid;
            *(uint2*)&ks_w[nxt + (idx >> 4) * QS + (idx & 15) * 4] =
                make_uint2(pk(kr[it].x, kr[it].y), pk(kr[it].z, kr[it].w));
        }
        {
            int tn = (kt + 2 < NKT) ? kt + 2 : NKT - 1;
            #pragma unroll
            for (int it = 0; it < 2; ++it) {
                int idx = it * 512 + tid;
                kr[it] = *(const float4*)&kb[((size_t)tn * KT + (idx >> 4)) * DH + (idx & 15) * 4];
            }
        }
        #pragma unroll
        for (int kgi = 0; kgi < 4; ++kgi) {
            f16x8 b0 = *(const f16x8*)&ks_r[cur + kgi * 16 * QS];
            f16x8 b1 = *(const f16x8*)&ks_r[cur + kgi * 16 * QS + 32];
            f32x4 acc = {0.f, 0.f, 0.f, 0.f};
            acc = MFMA(aq[0], b0, acc);
            acc = MFMA(aq[1], b1, acc);
            #pragma unroll
            for (int r = 0; r < 4; ++r)
                s1[r] += EXP2(acc[r]);
        }
        __syncthreads();
    }
    float inv1[4];
    #pragma unroll
    for (int s = 0; s < 4; ++s) {
        float v = s1[s];
        v += __shfl_xor(v, 1, 64);
        v += __shfl_xor(v, 2, 64);
        v += __shfl_xor(v, 4, 64);
        v += __shfl_xor(v, 8, 64);
        inv1[s] = 0.5f / v;      // e2 = exp2((acc*e1) * 0.5/s1)  [acc = 2L*log2e]
    }

    // =============== PASS 2: e2, O += e2*V ===============
    float l2[4] = {0, 0, 0, 0};
    f32x4 O[4];
    #pragma unroll
    for (int dt = 0; dt < 4; ++dt) O[dt] = (f32x4){0.f, 0.f, 0.f, 0.f};

    float4 vr[2];
    // prologue: Ks[0]<-K(0), Vt[0]<-V(0); kr<-K(1), vr<-V(1)
    #pragma unroll
    for (int it = 0; it < 2; ++it) {
        int idx = it * 512 + tid;
        kr[it] = *(const float4*)&kb[((size_t)(idx >> 4)) * DH + (idx & 15) * 4];
    }
    #pragma unroll
    for (int it = 0; it < 2; ++it) {
        int idx = it * 512 + tid;
        *(uint2*)&ks_w[(idx >> 4) * QS + (idx & 15) * 4] =
            make_uint2(pk(kr[it].x, kr[it].y), pk(kr[it].z, kr[it].w));
    }
    {
        const float* vs = vb + ((size_t)2 * vp) * DH + vgr * 4;
        vr[0] = *(const float4*)(vs);
        vr[1] = *(const float4*)(vs + DH);
        #pragma unroll
        for (int j = 0; j < 4; ++j)
            *(unsigned*)&vt_w[j * QS] =
                pk(((const float*)&vr[0])[j], ((const float*)&vr[1])[j]);
        const float* vs1 = vb + ((size_t)KT + 2 * vp) * DH + vgr * 4;
        vr[0] = *(const float4*)(vs1);
        vr[1] = *(const float4*)(vs1 + DH);
    }
    #pragma unroll
    for (int it = 0; it < 2; ++it) {
        int idx = it * 512 + tid;
        kr[it] = *(const float4*)&kb[((size_t)KT + (idx >> 4)) * DH + (idx & 15) * 4];
    }
    __syncthreads();

    for (int kt = 0; kt < NKT; ++kt) {
        const int cur = (kt & 1) * KSB, nxt = KSB - cur;
        // stage next K/V tile into the other buffers (overlaps all compute below)
        #pragma unroll
        for (int it = 0; it < 2; ++it) {
            int idx = it * 512 + tid;
            *(uint2*)&ks_w[nxt + (idx >> 4) * QS + (idx & 15) * 4] =
                make_uint2(pk(kr[it].x, kr[it].y), pk(kr[it].z, kr[it].w));
        }
        #pragma unroll
        for (int j = 0; j < 4; ++j)
            *(unsigned*)&vt_w[nxt + j * QS] =
                pk(((const float*)&vr[0])[j], ((const float*)&vr[1])[j]);
        // QK^T on Ks[cur] + softmax chain + Ps writes (wave-private, lgkmcnt-ordered)
        #pragma unroll
        for (int kgi = 0; kgi < 4; ++kgi) {
            f16x8 b0 = *(const f16x8*)&ks_r[cur + kgi * 16 * QS];
            f16x8 b1 = *(const f16x8*)&ks_r[cur + kgi * 16 * QS + 32];
            f32x4 acc = {0.f, 0.f, 0.f, 0.f};
            acc = MFMA(aq[0], b0, acc);
            acc = MFMA(aq[1], b1, acc);
            #pragma unroll
            for (int r = 0; r < 4; ++r) {
                float a  = acc[r];
                float e1 = EXP2(a);
                float e2 = EXP2((a * e1) * inv1[r]);
                l2[r] += e2;
                ps_w[r * QS + kgi * 16] = (f16)e2;
            }
        }
        // prefetch K(kt+2), V(kt+2) (clamped; loads in flight during PV)
        {
            int tn = (kt + 2 < NKT) ? kt + 2 : NKT - 1;
            #pragma unroll
            for (int it = 0; it < 2; ++it) {
                int idx = it * 512 + tid;
                kr[it] = *(const float4*)&kb[((size_t)tn * KT + (idx >> 4)) * DH + (idx & 15) * 4];
            }
            const float* vs = vb + ((size_t)tn * KT + 2 * vp) * DH + vgr * 4;
            vr[0] = *(const float4*)(vs);
            vr[1] = *(const float4*)(vs + DH);
        }
        // PV from wave-private Ps + Vt[cur] (written last iteration)
        #pragma unroll
        for (int kc = 0; kc < 2; ++kc) {
            f16x8 ap = *(const f16x8*)&ps_r[kc * 32];
            #pragma unroll
            for (int dt = 0; dt < 4; ++dt) {
                f16x8 bv = *(const f16x8*)&vt_r[cur + dt * 16 * QS + kc * 32];
                O[dt] = MFMA(ap, bv, O[dt]);
            }
        }
        __syncthreads();   // swap: protects Ks/Vt cur<->nxt for next iteration
    }

    // ---- finalize ----
    float invl2[4];
    #pragma unroll
    for (int s = 0; s < 4; ++s) {
        float v = l2[s];
        v += __shfl_xor(v, 1, 64);
        v += __shfl_xor(v, 2, 64);
        v += __shfl_xor(v, 4, 64);
        v += __shfl_xor(v, 8, 64);
        invl2[s] = 1.0f / v;
    }
    #pragma unroll
    for (int dt = 0; dt < 4; ++dt)
        #pragma unroll
        for (int r = 0; r < 4; ++r) {
            int row = q0 + wv * 16 + q4 * 4 + r;
            ob[(size_t)row * DH + dt * 16 + l15] = O[dt][r] * invl2[r];
        }
}

extern "C" void kernel_launch(void* const* d_in, const int* in_sizes, int n_in,
                              void* d_out, int out_size, void* d_ws, size_t ws_size,
                              hipStream_t stream) {
    const float* q = (const float*)d_in[0];
    const float* k = (const float*)d_in[1];
    const float* v = (const float*)d_in[2];
    const float* s = (const float*)d_in[3];
    float* out = (float*)d_out;
    dim3 grid(32 * 16);   // bh = blockIdx&31 (XCD swizzle), q-tile = blockIdx>>5
    stk_attn_mfma<<<grid, 512, 0, stream>>>(q, k, v, s, out);
}